// Round 12
// baseline (35.552 us; speedup 1.0000x reference)
//
#include <hip/hip_runtime.h>
#include <math.h>

#define PI_F    3.14159265358979323846f
#define TWO_PI  6.28318530717958647692f
#define HALF_PI 1.57079632679489661923f

__device__ __forceinline__ float frcp(float x)  { return __builtin_amdgcn_rcpf(x); }
__device__ __forceinline__ float frsq(float x)  { return __builtin_amdgcn_rsqf(x); }
__device__ __forceinline__ float fsqrt(float x) { return __builtin_amdgcn_sqrtf(x); }

// atan2(y,x) mapped to [0, 2pi). A&S 4.4.49 poly, |err| <= 1e-5 rad.
__device__ __forceinline__ float fast_atan2_2pi(float y, float x) {
    float ax = fabsf(x), ay = fabsf(y);
    float mx = fmaxf(ax, ay), mn = fminf(ax, ay);
    float a  = (mx > 0.0f) ? mn * frcp(mx) : 0.0f;
    float s  = a * a;
    float r  = fmaf(s, fmaf(s, fmaf(s, fmaf(s, 0.0208351f, -0.085133f),
                                    0.180141f), -0.3302995f), 0.9998660f) * a;
    if (ay > ax) r = HALF_PI - r;
    if (x < 0.0f) r = PI_F - r;
    return (y < 0.0f) ? (TWO_PI - r) : r;
}

// Shared per-item body: 8-lane group, lane j handles comps 8j..8j+7.
// Returns ldj via pointer; writes the rotation matrix rows if j==0.
__device__ __forceinline__ void item_body(
    const float* __restrict__ rot, const float* __restrict__ cond,
    float* __restrict__ out, size_t item, int j,
    int p0, int p1, int p2, bool swapc, float* ldj_out)
{
    const float* C = cond + item * 256;
    float4 pwa = *(const float4*)(C + 8 * j);
    float4 pwb = *(const float4*)(C + 8 * j + 4);
    const float* W = C + 64 + 24 * j;
    float4 f0 = ((const float4*)W)[0];
    float4 f1 = ((const float4*)W)[1];
    float4 f2 = ((const float4*)W)[2];
    float4 f3 = ((const float4*)W)[3];
    float4 f4 = ((const float4*)W)[4];
    float4 f5 = ((const float4*)W)[5];

    const float* R = rot + item * 9;
    float x0 = R[p0], x1 = R[3 + p0], x2 = R[6 + p0];
    float y0 = R[p1], y1 = R[3 + p1], y2 = R[6 + p1];

    float xn2    = x0 * x0 + x1 * x1 + x2 * x2;
    float inv_xn = frsq(xn2);
    float xn     = xn2 * inv_xn;
    float xy     = x0 * y0 + x1 * y1 + x2 * y2;
    float yn2    = y0 * y0 + y1 * y1 + y2 * y2;
    float negA   = yn2 - 2.0f;

    float cv0 = x1 * y2 - x2 * y1;
    float cv1 = x2 * y0 - x0 * y2;
    float cv2 = x0 * y1 - x1 * y0;
    float inv_cn = frsq(cv0 * cv0 + cv1 * cv1 + cv2 * cv2);
    float v0 = cv0 * inv_cn, v1 = cv1 * inv_cn, v2 = cv2 * inv_cn;

    float PW[8] = {pwa.x, pwa.y, pwa.z, pwa.w, pwb.x, pwb.y, pwb.z, pwb.w};
    float W0[8] = {f0.x, f0.w, f1.z, f2.y, f3.x, f3.w, f4.z, f5.y};
    float W1[8] = {f0.y, f1.x, f1.w, f2.z, f3.y, f4.x, f4.w, f5.z};
    float W2[8] = {f0.z, f1.y, f2.x, f2.w, f3.z, f4.y, f5.x, f5.w};

    float pp = 0.0f, pa = 0.0f, pd = 0.0f;
    #pragma unroll
    for (int cc = 0; cc < 8; ++cc) {
        float w0 = W0[cc], w1 = W1[cc], w2 = W2[cc];
        float yw  = y0 * w0 + y1 * w1 + y2 * w2;
        float wp2 = w0 * w0 + w1 * w1 + w2 * w2;
        float xwp = x0 * w0 + x1 * w1 + x2 * w2;
        float vwp = v0 * w0 + v1 * w1 + v2 * w2;
        float qn2 = fmaxf(fmaf(yw * yw, negA, wp2), 0.0f);  // ||proj w||^2
        float sc  = 0.7f * frcp(1.0f + fsqrt(qn2));
        float wn2 = (sc * sc) * qn2;
        float xw  = sc * fmaf(-xy, yw, xwp);            // x . w
        float zwn2 = fmaf(-2.0f, xw, xn2 + wn2);        // ||x-w||^2
        float c   = (1.0f - wn2) * frcp(zwn2);
        float cp1 = c + 1.0f;
        float hv  = -(cp1 * (sc * vwp));                // h.v
        float hr  = fmaf(cp1, xw * inv_xn, -(c * xn));  // h.r
        float ang = fast_atan2_2pi(hv, hr);
        float p   = __logf(1.0f + __expf(PW[cc]));      // softplus
        pp += p; pa = fmaf(p, ang, pa); pd = fmaf(p, c, pd);
    }

    #pragma unroll
    for (int off = 4; off >= 1; off >>= 1) {
        pp += __shfl_xor(pp, off, 64);
        pa += __shfl_xor(pa, off, 64);
        pd += __shfl_xor(pd, off, 64);
    }

    float ip   = frcp(pp);
    float angT = pa * ip;
    *ldj_out   = __logf(pd * ip);

    if (j == 0) {
        float sa, ca;
        __sincosf(angT, &sa, &ca);
        float r0 = -x0 * inv_xn, r1 = -x1 * inv_xn, r2 = -x2 * inv_xn;
        float t0 = fmaf(r0, ca, v0 * sa);
        float t1 = fmaf(r1, ca, v1 * sa);
        float t2 = fmaf(r2, ca, v2 * sa);

        float u0, u1, u2;
        if (swapc) {               // tz = cross(tx, y)
            u0 = t1 * y2 - t2 * y1;
            u1 = t2 * y0 - t0 * y2;
            u2 = t0 * y1 - t1 * y0;
        } else {                   // tz = cross(y, tx)
            u0 = y1 * t2 - y2 * t1;
            u1 = y2 * t0 - y0 * t2;
            u2 = y0 * t1 - y1 * t0;
        }
        float iun = frsq(u0 * u0 + u1 * u1 + u2 * u2);
        u0 *= iun; u1 *= iun; u2 *= iun;

        float* T = out + item * 9;
        T[p0] = t0; T[3 + p0] = t1; T[6 + p0] = t2;
        T[p1] = y0; T[3 + p1] = y1; T[6 + p1] = y2;
        T[p2] = u0; T[3 + p2] = u1; T[6 + p2] = u2;
    }
}

__device__ __forceinline__ void read_perm(const void* perm, int& p0, int& p1, int& p2) {
    const int* pi = (const int*)perm;
    p0 = pi[0]; p1 = pi[1]; p2 = pi[2];
    bool pok = ((unsigned)p0 < 3u) && ((unsigned)p1 < 3u) && ((unsigned)p2 < 3u)
               && (p0 != p1) && (p0 != p2) && (p1 != p2);
    if (!pok) {
        const long long* pl = (const long long*)perm;
        p0 = (int)pl[0]; p1 = (int)pl[1]; p2 = (int)pl[2];
    }
}

// Main kernel: 256-thread blocks, 4 waves, each wave ONE octet of items.
// No LDS, no __syncthreads, VGPR forced <= 64 (launch_bounds min 8
// waves/EU) so up to 32 waves/CU are co-resident -> maximal concurrent
// load streams. ldj partials go to ws[item]; a second kernel reduces.
__global__ __launch_bounds__(256, 8)
void mobius_main(const float* __restrict__ rot,
                 const float* __restrict__ cond,
                 const void* __restrict__ perm,
                 float* __restrict__ out,
                 float* __restrict__ ws,
                 int total_items)
{
    const int wave = threadIdx.x >> 6;
    const int lane = threadIdx.x & 63;
    const int sub  = lane >> 3;
    const int j    = lane & 7;

    int p0, p1, p2;
    read_perm(perm, p0, p1, p2);
    const int dd = p1 - p0;
    const bool swapc = (dd == 1 || dd == -2);

    const long long oct = (long long)blockIdx.x * 4 + wave;
    const long long it  = oct * 8 + sub;
    if (it >= total_items) return;
    const size_t item = (size_t)it;

    float ldj;
    item_body(rot, cond, out, item, j, p0, p1, p2, swapc, &ldj);
    if (j == 0) ws[item] = ldj;
}

// Sum N ldj partials per batch row (fixed order -> deterministic).
__global__ __launch_bounds__(256)
void ldj_reduce(const float* __restrict__ ws, float* __restrict__ out,
                int B, int N, long long out_off)
{
    int b = blockIdx.x * 256 + threadIdx.x;
    if (b >= B) return;
    const float* p = ws + (size_t)b * N;
    float acc = 0.0f;
    for (int n = 0; n < N; ++n) acc += p[n];
    out[out_off + b] = acc;
}

// Fallback (ws too small): r11 single-kernel — 7 waves, 8 items/wave,
// 8 batch rows per block, ldj reduced in LDS.
__global__ __launch_bounds__(448, 4)
void mobius_fused(const float* __restrict__ rot,
                  const float* __restrict__ cond,
                  const void* __restrict__ perm,
                  float* __restrict__ out,
                  int B, int N)
{
    const int wave = threadIdx.x >> 6;
    const int lane = threadIdx.x & 63;
    const int sub  = lane >> 3;
    const int j    = lane & 7;
    const int nwav = blockDim.x >> 6;

    const int b0   = blockIdx.x * 8;
    const int nb   = min(8, B - b0);
    const int nit  = N * nb;
    const int noct = (nit + 7) >> 3;

    int p0, p1, p2;
    read_perm(perm, p0, p1, p2);
    const int dd = p1 - p0;
    const bool swapc = (dd == 1 || dd == -2);

    __shared__ float s_ldj[192];
    const size_t base_item = (size_t)b0 * N;

    for (int q = wave; q < noct; q += nwav) {
        const int  i0    = 8 * q + sub;
        const bool valid = (i0 < nit);
        const size_t item = base_item + (valid ? i0 : 0);
        float ldj;
        item_body(rot, cond, out, item, j, p0, p1, p2, swapc, &ldj);
        if (j == 0 && valid) s_ldj[i0] = ldj;
    }

    __syncthreads();
    if (threadIdx.x < nb) {
        float acc = 0.0f;
        for (int n = 0; n < N; ++n) acc += s_ldj[threadIdx.x * N + n];
        out[(size_t)B * N * 9 + b0 + threadIdx.x] = acc;
    }
}

extern "C" void kernel_launch(void* const* d_in, const int* in_sizes, int n_in,
                              void* d_out, int out_size, void* d_ws, size_t ws_size,
                              hipStream_t stream) {
    const float* rot  = (const float*)d_in[0];
    const float* cond = (const float*)d_in[1];
    const void*  perm = d_in[2];
    float* out = (float*)d_out;

    int items = in_sizes[0] / 9;           // B*N
    int B = out_size - items * 9;          // out = items*9 trot + B ldj
    int N = items / B;

    if (ws_size >= (size_t)items * sizeof(float)) {
        long long octs = ((long long)items + 7) / 8;
        int grid1 = (int)((octs + 3) / 4);
        mobius_main<<<dim3(grid1), dim3(256), 0, stream>>>(
            rot, cond, perm, out, (float*)d_ws, items);
        int grid2 = (B + 255) / 256;
        ldj_reduce<<<dim3(grid2), dim3(256), 0, stream>>>(
            (const float*)d_ws, out, B, N, (long long)items * 9);
    } else {
        int grid = (B + 7) / 8;
        mobius_fused<<<dim3(grid), dim3(448), 0, stream>>>(rot, cond, perm, out, B, N);
    }
}